// Round 1
// baseline (794.304 us; speedup 1.0000x reference)
//
#include <hip/hip_runtime.h>
#include <hip/hip_bf16.h>

#define NEG_INF -1e20f

// ---------------------------------------------------------------------------
// K1: ctx_fc[r, h] = relu( sum_d context[r, d] * W[h, d] )
// M=16384 rows, H=512, K=512.  Tile 128x128, BK=32, 8x8 per thread.
// ---------------------------------------------------------------------------
__global__ __launch_bounds__(256, 2) void gemm_relu(const float* __restrict__ A,
                                                    const float* __restrict__ W,
                                                    float* __restrict__ C) {
    __shared__ float As[32][132];
    __shared__ float Bs[32][132];

    const int t  = threadIdx.x;
    const int tx = t & 15;        // -> H dim (8 cols)
    const int ty = t >> 4;        // -> M dim (8 rows)
    const int mBase = blockIdx.x * 128;
    const int hBase = blockIdx.y * 128;

    float acc[8][8] = {};

    for (int kt = 0; kt < 512; kt += 32) {
        // stage A-tile (rows mBase..+128, cols kt..+32) and W-tile, transposed into LDS
#pragma unroll
        for (int i = 0; i < 4; ++i) {
            int slot = t + i * 256;          // 0..1023
            int row  = slot >> 3;            // 0..127
            int kv   = slot & 7;             // 0..7  (float4 along K)
            float4 a = *(const float4*)(A + (size_t)(mBase + row) * 512 + kt + kv * 4);
            As[kv * 4 + 0][row] = a.x;
            As[kv * 4 + 1][row] = a.y;
            As[kv * 4 + 2][row] = a.z;
            As[kv * 4 + 3][row] = a.w;
            float4 b = *(const float4*)(W + (size_t)(hBase + row) * 512 + kt + kv * 4);
            Bs[kv * 4 + 0][row] = b.x;
            Bs[kv * 4 + 1][row] = b.y;
            Bs[kv * 4 + 2][row] = b.z;
            Bs[kv * 4 + 3][row] = b.w;
        }
        __syncthreads();
#pragma unroll
        for (int kk = 0; kk < 32; ++kk) {
            float aF[8], bF[8];
            *(float4*)&aF[0] = *(const float4*)&As[kk][ty * 8];
            *(float4*)&aF[4] = *(const float4*)&As[kk][ty * 8 + 4];
            *(float4*)&bF[0] = *(const float4*)&Bs[kk][tx * 8];
            *(float4*)&bF[4] = *(const float4*)&Bs[kk][tx * 8 + 4];
#pragma unroll
            for (int i = 0; i < 8; ++i)
#pragma unroll
                for (int j = 0; j < 8; ++j)
                    acc[i][j] = fmaf(aF[i], bF[j], acc[i][j]);
        }
        __syncthreads();
    }

#pragma unroll
    for (int i = 0; i < 8; ++i) {
        int r = mBase + ty * 8 + i;
        float* crow = C + (size_t)r * 512 + hBase + tx * 8;
        float4 o0 = make_float4(fmaxf(acc[i][0], 0.f), fmaxf(acc[i][1], 0.f),
                                fmaxf(acc[i][2], 0.f), fmaxf(acc[i][3], 0.f));
        float4 o1 = make_float4(fmaxf(acc[i][4], 0.f), fmaxf(acc[i][5], 0.f),
                                fmaxf(acc[i][6], 0.f), fmaxf(acc[i][7], 0.f));
        *(float4*)crow       = o0;
        *(float4*)(crow + 4) = o1;
    }
}

// ---------------------------------------------------------------------------
// K2: att[b, n, m] = dot(F[b,n,:], F[b,m,:])  (masked), written to out.
// Per batch: M=N=2048, K=512.  Same tiling as K1.
// ---------------------------------------------------------------------------
__global__ __launch_bounds__(256, 2) void gemm_att(const float* __restrict__ F,
                                                   const int* __restrict__ mask,
                                                   float* __restrict__ out) {
    __shared__ float As[32][132];
    __shared__ float Bs[32][132];

    const int t  = threadIdx.x;
    const int tx = t & 15;        // -> m dim
    const int ty = t >> 4;        // -> n dim
    const int b     = blockIdx.z;
    const int mBase = blockIdx.x * 128;
    const int nBase = blockIdx.y * 128;
    const float* Fb = F + (size_t)b * 2048 * 512;

    float acc[8][8] = {};

    for (int kt = 0; kt < 512; kt += 32) {
#pragma unroll
        for (int i = 0; i < 4; ++i) {
            int slot = t + i * 256;
            int row  = slot >> 3;
            int kv   = slot & 7;
            float4 a = *(const float4*)(Fb + (size_t)(nBase + row) * 512 + kt + kv * 4);
            As[kv * 4 + 0][row] = a.x;
            As[kv * 4 + 1][row] = a.y;
            As[kv * 4 + 2][row] = a.z;
            As[kv * 4 + 3][row] = a.w;
            float4 bb = *(const float4*)(Fb + (size_t)(mBase + row) * 512 + kt + kv * 4);
            Bs[kv * 4 + 0][row] = bb.x;
            Bs[kv * 4 + 1][row] = bb.y;
            Bs[kv * 4 + 2][row] = bb.z;
            Bs[kv * 4 + 3][row] = bb.w;
        }
        __syncthreads();
#pragma unroll
        for (int kk = 0; kk < 32; ++kk) {
            float aF[8], bF[8];
            *(float4*)&aF[0] = *(const float4*)&As[kk][ty * 8];
            *(float4*)&aF[4] = *(const float4*)&As[kk][ty * 8 + 4];
            *(float4*)&bF[0] = *(const float4*)&Bs[kk][tx * 8];
            *(float4*)&bF[4] = *(const float4*)&Bs[kk][tx * 8 + 4];
#pragma unroll
            for (int i = 0; i < 8; ++i)
#pragma unroll
                for (int j = 0; j < 8; ++j)
                    acc[i][j] = fmaf(aF[i], bF[j], acc[i][j]);
        }
        __syncthreads();
    }

    const int* mb = mask + b * 2048;
    int colm[8];
#pragma unroll
    for (int j = 0; j < 8; ++j) colm[j] = mb[mBase + tx * 8 + j];

#pragma unroll
    for (int i = 0; i < 8; ++i) {
        int n  = nBase + ty * 8 + i;
        int rm = mb[n];
        float o[8];
#pragma unroll
        for (int j = 0; j < 8; ++j)
            o[j] = (rm && colm[j]) ? acc[i][j] : NEG_INF;
        float* orow = out + ((size_t)b * 2048 + n) * 2048 + mBase + tx * 8;
        *(float4*)orow       = make_float4(o[0], o[1], o[2], o[3]);
        *(float4*)(orow + 4) = make_float4(o[4], o[5], o[6], o[7]);
    }
}

// ---------------------------------------------------------------------------
// K3: per row (b*2048+n): keep top-10, fill rest with -1e20.  In-place on out.
// One 256-thread block per row.
// ---------------------------------------------------------------------------
__device__ inline unsigned fkey(float f) {
    unsigned u = __float_as_uint(f);
    return (u & 0x80000000u) ? ~u : (u | 0x80000000u);
}

__global__ __launch_bounds__(256) void topk_rows(float* __restrict__ att) {
    __shared__ float vals[2048];
    __shared__ unsigned long long wave_best[4];
    __shared__ int   top_idx[10];
    __shared__ float top_val[10];

    const int t = threadIdx.x;
    float* row  = att + (size_t)blockIdx.x * 2048;

    // stage row into LDS
    float4 a = ((const float4*)row)[t];
    float4 b = ((const float4*)row)[t + 256];
    ((float4*)vals)[t]       = a;
    ((float4*)vals)[t + 256] = b;
    __syncthreads();

    for (int it = 0; it < 10; ++it) {
        // local argmax over 8 contiguous elements (ascending scan => lowest idx on tie)
        float bv = -INFINITY;
        int   bi = 0;
#pragma unroll
        for (int j = 0; j < 8; ++j) {
            float v = vals[t * 8 + j];
            if (v > bv) { bv = v; bi = t * 8 + j; }
        }
        // pack: high 32 = order-preserving float key, low 32 = ~idx (max => lowest idx)
        unsigned long long pk =
            ((unsigned long long)fkey(bv) << 32) | (unsigned)(~(unsigned)bi);
#pragma unroll
        for (int off = 32; off > 0; off >>= 1) {
            unsigned long long o = __shfl_down(pk, off, 64);
            if (o > pk) pk = o;
        }
        if ((t & 63) == 0) wave_best[t >> 6] = pk;
        __syncthreads();
        if (t == 0) {
            unsigned long long m = wave_best[0];
#pragma unroll
            for (int w = 1; w < 4; ++w)
                if (wave_best[w] > m) m = wave_best[w];
            int idx = (int)(~(unsigned)(m & 0xffffffffu));
            top_idx[it] = idx;
            top_val[it] = vals[idx];
            vals[idx]   = -INFINITY;   // remove from further consideration
        }
        __syncthreads();
    }

    // rewrite row: -1e20 everywhere except the 10 winners (race-free compare-fill)
    float o[8];
#pragma unroll
    for (int j = 0; j < 8; ++j) {
        int p   = t * 8 + j;
        float v = NEG_INF;
#pragma unroll
        for (int q = 0; q < 10; ++q)
            if (top_idx[q] == p) v = top_val[q];
        o[j] = v;
    }
    ((float4*)row)[t * 2]     = make_float4(o[0], o[1], o[2], o[3]);
    ((float4*)row)[t * 2 + 1] = make_float4(o[4], o[5], o[6], o[7]);
}

// ---------------------------------------------------------------------------
extern "C" void kernel_launch(void* const* d_in, const int* in_sizes, int n_in,
                              void* d_out, int out_size, void* d_ws, size_t ws_size,
                              hipStream_t stream) {
    const float* ctx  = (const float*)d_in[0];   // [8, 2048, 512]
    const float* W    = (const float*)d_in[1];   // [512, 512]
    const int*   mask = (const int*)d_in[2];     // [8, 2048]
    float* out = (float*)d_out;                  // [8, 2048, 2048]
    float* Fc  = (float*)d_ws;                   // ctx_fc [16384, 512] = 33.5 MB

    dim3 blk(256);
    // K1: ctx_fc = relu(context @ W^T)
    gemm_relu<<<dim3(128, 4), blk, 0, stream>>>(ctx, W, Fc);
    // K2: att = F F^T (masked) -> d_out (scratch use)
    gemm_att<<<dim3(16, 16, 8), blk, 0, stream>>>(Fc, mask, out);
    // K3: in-place top-10 per row
    topk_rows<<<dim3(16384), blk, 0, stream>>>(out);
}

// Round 2
// 488.713 us; speedup vs baseline: 1.6253x; 1.6253x over previous
//
#include <hip/hip_runtime.h>
#include <hip/hip_bf16.h>

#define NEG_INF -1e20f

typedef __bf16 bf16x8 __attribute__((ext_vector_type(8)));
typedef float  f32x4  __attribute__((ext_vector_type(4)));

__device__ inline unsigned short f2bf(float x) {            // RNE, no NaN inputs
    unsigned u = __float_as_uint(x);
    unsigned r = u + 0x7fffu + ((u >> 16) & 1u);
    return (unsigned short)(r >> 16);
}
__device__ inline float bf2f(unsigned short h) {
    return __uint_as_float((unsigned)h << 16);
}

// ---------------------------------------------------------------------------
// K1: acc = context @ W^T (fp32 VALU), epilogue: relu + split into bf16 hi/lo.
// M=16384, H=512, K=512. Tile 128x128, BK=32. Per thread 8x8 split 4+4 so LDS
// reads are stride-16B (2-way, free); pad 133 makes staging writes 2-way.
// ---------------------------------------------------------------------------
__global__ __launch_bounds__(256, 2) void gemm_relu_split(
        const float* __restrict__ A, const float* __restrict__ W,
        unsigned short* __restrict__ Fhi, unsigned short* __restrict__ Flo) {
    __shared__ float As[32][133];
    __shared__ float Bs[32][133];

    const int t  = threadIdx.x;
    const int tx = t & 15;        // -> H dim
    const int ty = t >> 4;        // -> M dim
    const int mBase = blockIdx.x * 128;
    const int hBase = blockIdx.y * 128;

    float acc[8][8] = {};

    for (int kt = 0; kt < 512; kt += 32) {
#pragma unroll
        for (int i = 0; i < 4; ++i) {
            int slot = t + i * 256;
            int row  = slot >> 3;
            int kv   = slot & 7;
            float4 a = *(const float4*)(A + (size_t)(mBase + row) * 512 + kt + kv * 4);
            As[kv * 4 + 0][row] = a.x;
            As[kv * 4 + 1][row] = a.y;
            As[kv * 4 + 2][row] = a.z;
            As[kv * 4 + 3][row] = a.w;
            float4 b = *(const float4*)(W + (size_t)(hBase + row) * 512 + kt + kv * 4);
            Bs[kv * 4 + 0][row] = b.x;
            Bs[kv * 4 + 1][row] = b.y;
            Bs[kv * 4 + 2][row] = b.z;
            Bs[kv * 4 + 3][row] = b.w;
        }
        __syncthreads();
#pragma unroll
        for (int kk = 0; kk < 32; ++kk) {
            float aF[8], bF[8];
            *(float4*)&aF[0] = *(const float4*)&As[kk][ty * 4];
            *(float4*)&aF[4] = *(const float4*)&As[kk][64 + ty * 4];
            *(float4*)&bF[0] = *(const float4*)&Bs[kk][tx * 4];
            *(float4*)&bF[4] = *(const float4*)&Bs[kk][64 + tx * 4];
#pragma unroll
            for (int i = 0; i < 8; ++i)
#pragma unroll
                for (int j = 0; j < 8; ++j)
                    acc[i][j] = fmaf(aF[i], bF[j], acc[i][j]);
        }
        __syncthreads();
    }

#pragma unroll
    for (int i = 0; i < 8; ++i) {
        int r = mBase + (i >> 2) * 64 + ty * 4 + (i & 3);
#pragma unroll
        for (int half = 0; half < 2; ++half) {
            int c0 = hBase + half * 64 + tx * 4;
            ushort4 h, l;
            float v0 = fmaxf(acc[i][half * 4 + 0], 0.f);
            float v1 = fmaxf(acc[i][half * 4 + 1], 0.f);
            float v2 = fmaxf(acc[i][half * 4 + 2], 0.f);
            float v3 = fmaxf(acc[i][half * 4 + 3], 0.f);
            h.x = f2bf(v0); h.y = f2bf(v1); h.z = f2bf(v2); h.w = f2bf(v3);
            l.x = f2bf(v0 - bf2f(h.x)); l.y = f2bf(v1 - bf2f(h.y));
            l.z = f2bf(v2 - bf2f(h.z)); l.w = f2bf(v3 - bf2f(h.w));
            *(ushort4*)(Fhi + (size_t)r * 512 + c0) = h;
            *(ushort4*)(Flo + (size_t)r * 512 + c0) = l;
        }
    }
}

// ---------------------------------------------------------------------------
// K2: att = F F^T via bf16x3 MFMA emulation (hi*hi + hi*lo + lo*hi).
// Tile 128(n) x 128(m), BK=32. 4 waves, each 64x64 = 4x4 of 16x16x32.
// LDS: 4 planes (Ahi,Alo,Bhi,Blo) of 128x32 bf16, 16B chunks XOR-swizzled
// with c ^ ((row>>1)&3) so ds_read_b128 fragment reads are conflict-light.
// Staged via global_load_lds width=16 (lane-contiguous dest, swizzle applied
// on the global source address).
// ---------------------------------------------------------------------------
__global__ __launch_bounds__(256, 2) void att_mfma(
        const unsigned short* __restrict__ Fhi, const unsigned short* __restrict__ Flo,
        const int* __restrict__ mask, float* __restrict__ out) {
    __shared__ char lds[32768];

    const int t     = threadIdx.x;
    const int b     = blockIdx.z;
    const int mBase = blockIdx.x * 128;
    const int nBase = blockIdx.y * 128;
    const int w    = t >> 6, lane = t & 63;
    const int q    = lane >> 4, ln = lane & 15;
    const int wn   = (w >> 1) * 64;      // wave's n-offset in tile
    const int wm   = (w & 1) * 64;       // wave's m-offset in tile
    const size_t rowB = (size_t)b * 2048;

    f32x4 acc[4][4] = {};

    for (int kt = 0; kt < 512; kt += 32) {
        // ---- stage 4 planes: p0=Ahi(n) p1=Alo(n) p2=Bhi(m) p3=Blo(m)
#pragma unroll
        for (int p = 0; p < 4; ++p) {
            const unsigned short* plane = (p & 1) ? Flo : Fhi;
            int rbase = (p < 2) ? nBase : mBase;
#pragma unroll
            for (int r = 0; r < 2; ++r) {
                int chunk = r * 256 + t;          // 0..511 16B-chunks
                int row   = chunk >> 2;           // 0..127
                int cs    = chunk & 3;            // swizzled col slot
                int c     = cs ^ ((row >> 1) & 3);
                const unsigned short* g =
                    plane + ((rowB + rbase + row) * 512 + kt + c * 8);
                char* l = lds + p * 8192 + chunk * 16;
                __builtin_amdgcn_global_load_lds(
                    (const __attribute__((address_space(1))) void*)g,
                    (__attribute__((address_space(3))) void*)l, 16, 0, 0);
            }
        }
        __syncthreads();

        // ---- fragments: A[m=lane&15][k=q*8+j] layout; same for B
        bf16x8 ah[4], al[4], bh[4], bl[4];
#pragma unroll
        for (int i = 0; i < 4; ++i) {
            int mA = wn + i * 16 + ln;
            int oA = (mA * 4 + (q ^ ((mA >> 1) & 3))) * 16;
            ah[i] = *(const bf16x8*)(lds +     0 + oA);
            al[i] = *(const bf16x8*)(lds +  8192 + oA);
            int mB = wm + i * 16 + ln;
            int oB = (mB * 4 + (q ^ ((mB >> 1) & 3))) * 16;
            bh[i] = *(const bf16x8*)(lds + 16384 + oB);
            bl[i] = *(const bf16x8*)(lds + 24576 + oB);
        }
#pragma unroll
        for (int i = 0; i < 4; ++i)
#pragma unroll
            for (int j = 0; j < 4; ++j) {
                acc[i][j] = __builtin_amdgcn_mfma_f32_16x16x32_bf16(ah[i], bh[j], acc[i][j], 0, 0, 0);
                acc[i][j] = __builtin_amdgcn_mfma_f32_16x16x32_bf16(ah[i], bl[j], acc[i][j], 0, 0, 0);
                acc[i][j] = __builtin_amdgcn_mfma_f32_16x16x32_bf16(al[i], bh[j], acc[i][j], 0, 0, 0);
            }
        __syncthreads();
    }

    // ---- epilogue: C/D layout col=lane&15 (m), row=q*4+reg (n); mask + store
    const int* mb = mask + b * 2048;
    float* outB = out + (size_t)b * 2048 * 2048;
#pragma unroll
    for (int j = 0; j < 4; ++j) {
        int mg   = mBase + wm + j * 16 + ln;
        int mcol = mb[mg];
#pragma unroll
        for (int i = 0; i < 4; ++i) {
            int n0 = nBase + wn + i * 16 + q * 4;
#pragma unroll
            for (int r = 0; r < 4; ++r) {
                int   n  = n0 + r;
                float v  = ((mb[n] != 0) & (mcol != 0)) ? acc[i][j][r] : NEG_INF;
                outB[(size_t)n * 2048 + mg] = v;
            }
        }
    }
}

// ---------------------------------------------------------------------------
// K3: per-row top-10 -> keep winners, fill -1e20. Register-resident:
// packed key (fkey(v)<<32)|~idx, per-wave 10x argmax (shfl butterfly),
// then wave0 merges 4x10 candidates. Tie-break = lowest index (jax semantics).
// ---------------------------------------------------------------------------
__device__ inline unsigned fkey(float f) {
    unsigned u = __float_as_uint(f);
    return (u & 0x80000000u) ? ~u : (u | 0x80000000u);
}

__global__ __launch_bounds__(256) void topk_rows(float* __restrict__ att) {
    __shared__ unsigned long long cand[40];
    __shared__ int   top_i[10];
    __shared__ float top_v[10];

    const int t    = threadIdx.x;
    const int lane = t & 63;
    const int w    = t >> 6;
    float* row = att + (size_t)blockIdx.x * 2048;

    float4 a = ((const float4*)row)[2 * t];
    float4 c = ((const float4*)row)[2 * t + 1];
    float v[8] = {a.x, a.y, a.z, a.w, c.x, c.y, c.z, c.w};

    unsigned long long key[8];
#pragma unroll
    for (int j = 0; j < 8; ++j)
        key[j] = ((unsigned long long)fkey(v[j]) << 32) |
                 (unsigned)(~(unsigned)(t * 8 + j));

    // per-wave top-10 of its 512 elements
    for (int r = 0; r < 10; ++r) {
        unsigned long long m = key[0];
#pragma unroll
        for (int j = 1; j < 8; ++j) m = (key[j] > m) ? key[j] : m;
#pragma unroll
        for (int off = 1; off < 64; off <<= 1) {
            unsigned long long o = __shfl_xor(m, off, 64);
            m = (o > m) ? o : m;
        }
        if (lane == 0) cand[w * 10 + r] = m;
#pragma unroll
        for (int j = 0; j < 8; ++j)
            if (key[j] == m) key[j] = 0ull;
    }
    __syncthreads();

    // wave 0: top-10 of the 40 candidates
    if (w == 0) {
        unsigned long long k2 = (lane < 40) ? cand[lane] : 0ull;
        for (int r = 0; r < 10; ++r) {
            unsigned long long m = k2;
#pragma unroll
            for (int off = 1; off < 64; off <<= 1) {
                unsigned long long o = __shfl_xor(m, off, 64);
                m = (o > m) ? o : m;
            }
            if (lane == r) {
                unsigned hu = (unsigned)(m >> 32);
                unsigned fu = (hu & 0x80000000u) ? (hu ^ 0x80000000u) : ~hu;
                top_v[r] = __uint_as_float(fu);
                top_i[r] = (int)(~(unsigned)(m & 0xffffffffu));
            }
            if (k2 == m) k2 = 0ull;
        }
    }
    __syncthreads();

    float o[8];
#pragma unroll
    for (int j = 0; j < 8; ++j) {
        int p   = t * 8 + j;
        float x = NEG_INF;
#pragma unroll
        for (int r = 0; r < 10; ++r)
            if (top_i[r] == p) x = top_v[r];
        o[j] = x;
    }
    ((float4*)row)[2 * t]     = make_float4(o[0], o[1], o[2], o[3]);
    ((float4*)row)[2 * t + 1] = make_float4(o[4], o[5], o[6], o[7]);
}

// ---------------------------------------------------------------------------
extern "C" void kernel_launch(void* const* d_in, const int* in_sizes, int n_in,
                              void* d_out, int out_size, void* d_ws, size_t ws_size,
                              hipStream_t stream) {
    const float* ctx  = (const float*)d_in[0];   // [8, 2048, 512]
    const float* W    = (const float*)d_in[1];   // [512, 512]
    const int*   mask = (const int*)d_in[2];     // [8, 2048]
    float* out = (float*)d_out;                  // [8, 2048, 2048]

    unsigned short* Fhi = (unsigned short*)d_ws;         // [16384, 512] bf16
    unsigned short* Flo = Fhi + (size_t)16384 * 512;     // [16384, 512] bf16

    dim3 blk(256);
    gemm_relu_split<<<dim3(128, 4), blk, 0, stream>>>(ctx, W, Fhi, Flo);
    att_mfma<<<dim3(16, 16, 8), blk, 0, stream>>>(Fhi, Flo, mask, out);
    topk_rows<<<dim3(16384), blk, 0, stream>>>(out);
}

// Round 4
// 487.481 us; speedup vs baseline: 1.6294x; 1.0025x over previous
//
#include <hip/hip_runtime.h>
#include <hip/hip_bf16.h>

#define NEG_INF -1e20f

typedef __bf16 bf16x8 __attribute__((ext_vector_type(8)));
typedef float  f32x4  __attribute__((ext_vector_type(4)));

__device__ inline unsigned short f2bf(float x) {            // RNE, no NaN inputs
    unsigned u = __float_as_uint(x);
    unsigned r = u + 0x7fffu + ((u >> 16) & 1u);
    return (unsigned short)(r >> 16);
}
__device__ inline float bf2f(unsigned short h) {
    return __uint_as_float((unsigned)h << 16);
}

// ---------------------------------------------------------------------------
// K1: ctx_fc = relu(context @ W^T) in exact fp32 (k-ascending FMA chain ==
// bit-identical to the round-2 kernel that passed), epilogue splits to bf16
// hi/lo planes. M=16384, H=512, K=512.
// Tile 64(m) x 128(h), BK=32, 256 threads, per-thread 4(m) x 8(h) accs.
// A in LDS as [k][row] pad 68 (b128 reads broadcast, writes 4-way worst),
// B in LDS as [col][k] pad 36 (cols tx+16j -> b128 reads 2-way = free).
// Grid 256x4 = 1024 blocks = 4/CU (round-2's 512-block grid was the
// occupancy bottleneck: 2 blocks/CU, OccupancyPercent 23%).
// ---------------------------------------------------------------------------
__global__ __launch_bounds__(256, 4) void gemm_relu_fast(
        const float* __restrict__ A, const float* __restrict__ W,
        unsigned short* __restrict__ Fhi, unsigned short* __restrict__ Flo) {
    __shared__ float As[32][68];     // [k][row]
    __shared__ float Bs[128][36];    // [col][k]

    const int t  = threadIdx.x;
    const int tx = t & 15;           // -> h: cols tx + 16*j, j=0..7
    const int ty = t >> 4;           // -> m: rows ty*4 .. ty*4+3
    const int mBase = blockIdx.x * 64;
    const int hBase = blockIdx.y * 128;

    float acc[4][8] = {};

    for (int kt = 0; kt < 512; kt += 32) {
        // stage A: 64 rows x 32 k, transposed into [k][row]
#pragma unroll
        for (int i = 0; i < 2; ++i) {
            int slot = t + i * 256;          // 0..511
            int row  = slot >> 3;            // 0..63
            int kv   = slot & 7;             // float4 along k
            float4 a = *(const float4*)(A + (size_t)(mBase + row) * 512 + kt + kv * 4);
            As[kv * 4 + 0][row] = a.x;
            As[kv * 4 + 1][row] = a.y;
            As[kv * 4 + 2][row] = a.z;
            As[kv * 4 + 3][row] = a.w;
        }
        // stage B: 128 W-rows x 32 k, natural [col][k] (no transpose)
#pragma unroll
        for (int i = 0; i < 4; ++i) {
            int slot = t + i * 256;          // 0..1023
            int col  = slot >> 3;            // 0..127
            int kv   = slot & 7;
            float4 b = *(const float4*)(W + (size_t)(hBase + col) * 512 + kt + kv * 4);
            *(float4*)&Bs[col][kv * 4] = b;
        }
        __syncthreads();

#pragma unroll
        for (int kc = 0; kc < 8; ++kc) {     // k-chunks of 4
            float4 bv[8];
#pragma unroll
            for (int j = 0; j < 8; ++j)
                bv[j] = *(const float4*)&Bs[tx + 16 * j][kc * 4];
#pragma unroll
            for (int z = 0; z < 4; ++z) {    // k = kt + kc*4 + z, ascending
                float4 av = *(const float4*)&As[kc * 4 + z][ty * 4];
                float am[4] = {av.x, av.y, av.z, av.w};
                float bj[8] = {bv[0][z], bv[1][z], bv[2][z], bv[3][z],
                               bv[4][z], bv[5][z], bv[6][z], bv[7][z]};
#pragma unroll
                for (int m = 0; m < 4; ++m)
#pragma unroll
                    for (int j = 0; j < 8; ++j)
                        acc[m][j] = fmaf(am[m], bj[j], acc[m][j]);
            }
        }
        __syncthreads();
    }

    // epilogue: relu + bf16 hi/lo split (identical arithmetic to round 2)
#pragma unroll
    for (int m = 0; m < 4; ++m) {
        size_t rowOff = (size_t)(mBase + ty * 4 + m) * 512;
#pragma unroll
        for (int j = 0; j < 8; ++j) {
            int h = hBase + tx + 16 * j;
            float v = fmaxf(acc[m][j], 0.f);
            unsigned short hi = f2bf(v);
            unsigned short lo = f2bf(v - bf2f(hi));
            Fhi[rowOff + h] = hi;
            Flo[rowOff + h] = lo;
        }
    }
}

// ---------------------------------------------------------------------------
// K2: att = F F^T via bf16x3 MFMA emulation (hi*hi + hi*lo + lo*hi).
// VERBATIM from round 2 (passed, absmax 0.25).
// ---------------------------------------------------------------------------
__global__ __launch_bounds__(256, 2) void att_mfma(
        const unsigned short* __restrict__ Fhi, const unsigned short* __restrict__ Flo,
        const int* __restrict__ mask, float* __restrict__ out) {
    __shared__ char lds[32768];

    const int t     = threadIdx.x;
    const int b     = blockIdx.z;
    const int mBase = blockIdx.x * 128;
    const int nBase = blockIdx.y * 128;
    const int w    = t >> 6, lane = t & 63;
    const int q    = lane >> 4, ln = lane & 15;
    const int wn   = (w >> 1) * 64;
    const int wm   = (w & 1) * 64;
    const size_t rowB = (size_t)b * 2048;

    f32x4 acc[4][4] = {};

    for (int kt = 0; kt < 512; kt += 32) {
#pragma unroll
        for (int p = 0; p < 4; ++p) {
            const unsigned short* plane = (p & 1) ? Flo : Fhi;
            int rbase = (p < 2) ? nBase : mBase;
#pragma unroll
            for (int r = 0; r < 2; ++r) {
                int chunk = r * 256 + t;
                int row   = chunk >> 2;
                int cs    = chunk & 3;
                int c     = cs ^ ((row >> 1) & 3);
                const unsigned short* g =
                    plane + ((rowB + rbase + row) * 512 + kt + c * 8);
                char* l = lds + p * 8192 + chunk * 16;
                __builtin_amdgcn_global_load_lds(
                    (const __attribute__((address_space(1))) void*)g,
                    (__attribute__((address_space(3))) void*)l, 16, 0, 0);
            }
        }
        __syncthreads();

        bf16x8 ah[4], al[4], bh[4], bl[4];
#pragma unroll
        for (int i = 0; i < 4; ++i) {
            int mA = wn + i * 16 + ln;
            int oA = (mA * 4 + (q ^ ((mA >> 1) & 3))) * 16;
            ah[i] = *(const bf16x8*)(lds +     0 + oA);
            al[i] = *(const bf16x8*)(lds +  8192 + oA);
            int mB = wm + i * 16 + ln;
            int oB = (mB * 4 + (q ^ ((mB >> 1) & 3))) * 16;
            bh[i] = *(const bf16x8*)(lds + 16384 + oB);
            bl[i] = *(const bf16x8*)(lds + 24576 + oB);
        }
#pragma unroll
        for (int i = 0; i < 4; ++i)
#pragma unroll
            for (int j = 0; j < 4; ++j) {
                acc[i][j] = __builtin_amdgcn_mfma_f32_16x16x32_bf16(ah[i], bh[j], acc[i][j], 0, 0, 0);
                acc[i][j] = __builtin_amdgcn_mfma_f32_16x16x32_bf16(ah[i], bl[j], acc[i][j], 0, 0, 0);
                acc[i][j] = __builtin_amdgcn_mfma_f32_16x16x32_bf16(al[i], bh[j], acc[i][j], 0, 0, 0);
            }
        __syncthreads();
    }

    const int* mb = mask + b * 2048;
    float* outB = out + (size_t)b * 2048 * 2048;
#pragma unroll
    for (int j = 0; j < 4; ++j) {
        int mg   = mBase + wm + j * 16 + ln;
        int mcol = mb[mg];
#pragma unroll
        for (int i = 0; i < 4; ++i) {
            int n0 = nBase + wn + i * 16 + q * 4;
#pragma unroll
            for (int r = 0; r < 4; ++r) {
                int   n  = n0 + r;
                float v  = ((mb[n] != 0) & (mcol != 0)) ? acc[i][j][r] : NEG_INF;
                outB[(size_t)n * 2048 + mg] = v;
            }
        }
    }
}

// ---------------------------------------------------------------------------
// K3: per-row top-10 -> keep winners, fill -1e20. VERBATIM from round 2.
// ---------------------------------------------------------------------------
__device__ inline unsigned fkey(float f) {
    unsigned u = __float_as_uint(f);
    return (u & 0x80000000u) ? ~u : (u | 0x80000000u);
}

__global__ __launch_bounds__(256) void topk_rows(float* __restrict__ att) {
    __shared__ unsigned long long cand[40];
    __shared__ int   top_i[10];
    __shared__ float top_v[10];

    const int t    = threadIdx.x;
    const int lane = t & 63;
    const int w    = t >> 6;
    float* row = att + (size_t)blockIdx.x * 2048;

    float4 a = ((const float4*)row)[2 * t];
    float4 c = ((const float4*)row)[2 * t + 1];
    float v[8] = {a.x, a.y, a.z, a.w, c.x, c.y, c.z, c.w};

    unsigned long long key[8];
#pragma unroll
    for (int j = 0; j < 8; ++j)
        key[j] = ((unsigned long long)fkey(v[j]) << 32) |
                 (unsigned)(~(unsigned)(t * 8 + j));

    for (int r = 0; r < 10; ++r) {
        unsigned long long m = key[0];
#pragma unroll
        for (int j = 1; j < 8; ++j) m = (key[j] > m) ? key[j] : m;
#pragma unroll
        for (int off = 1; off < 64; off <<= 1) {
            unsigned long long o = __shfl_xor(m, off, 64);
            m = (o > m) ? o : m;
        }
        if (lane == 0) cand[w * 10 + r] = m;
#pragma unroll
        for (int j = 0; j < 8; ++j)
            if (key[j] == m) key[j] = 0ull;
    }
    __syncthreads();

    if (w == 0) {
        unsigned long long k2 = (lane < 40) ? cand[lane] : 0ull;
        for (int r = 0; r < 10; ++r) {
            unsigned long long m = k2;
#pragma unroll
            for (int off = 1; off < 64; off <<= 1) {
                unsigned long long o = __shfl_xor(m, off, 64);
                m = (o > m) ? o : m;
            }
            if (lane == r) {
                unsigned hu = (unsigned)(m >> 32);
                unsigned fu = (hu & 0x80000000u) ? (hu ^ 0x80000000u) : ~hu;
                top_v[r] = __uint_as_float(fu);
                top_i[r] = (int)(~(unsigned)(m & 0xffffffffu));
            }
            if (k2 == m) k2 = 0ull;
        }
    }
    __syncthreads();

    float o[8];
#pragma unroll
    for (int j = 0; j < 8; ++j) {
        int p   = t * 8 + j;
        float x = NEG_INF;
#pragma unroll
        for (int r = 0; r < 10; ++r)
            if (top_i[r] == p) x = top_v[r];
        o[j] = x;
    }
    ((float4*)row)[2 * t]     = make_float4(o[0], o[1], o[2], o[3]);
    ((float4*)row)[2 * t + 1] = make_float4(o[4], o[5], o[6], o[7]);
}

// ---------------------------------------------------------------------------
extern "C" void kernel_launch(void* const* d_in, const int* in_sizes, int n_in,
                              void* d_out, int out_size, void* d_ws, size_t ws_size,
                              hipStream_t stream) {
    const float* ctx  = (const float*)d_in[0];   // [8, 2048, 512]
    const float* W    = (const float*)d_in[1];   // [512, 512]
    const int*   mask = (const int*)d_in[2];     // [8, 2048]
    float* out = (float*)d_out;                  // [8, 2048, 2048]

    unsigned short* Fhi = (unsigned short*)d_ws;           // [16384, 512] bf16
    unsigned short* Flo = Fhi + (size_t)16384 * 512;

    dim3 blk(256);
    gemm_relu_fast<<<dim3(256, 4), blk, 0, stream>>>(ctx, W, Fhi, Flo);
    att_mfma<<<dim3(16, 16, 8), blk, 0, stream>>>(Fhi, Flo, mask, out);
    topk_rows<<<dim3(16384), blk, 0, stream>>>(out);
}

// Round 5
// 423.068 us; speedup vs baseline: 1.8775x; 1.1523x over previous
//
#include <hip/hip_runtime.h>
#include <hip/hip_bf16.h>

#define NEG_INF -1e20f

typedef __bf16 bf16x8 __attribute__((ext_vector_type(8)));
typedef float  f32x4  __attribute__((ext_vector_type(4)));

__device__ inline unsigned short f2bf(float x) {            // RNE, no NaN inputs
    unsigned u = __float_as_uint(x);
    unsigned r = u + 0x7fffu + ((u >> 16) & 1u);
    return (unsigned short)(r >> 16);
}
__device__ inline float bf2f(unsigned short h) {
    return __uint_as_float((unsigned)h << 16);
}

// ---------------------------------------------------------------------------
// K0: split fp32 -> 3 bf16 planes (x ~= b1 + b2 + b3, residual ~2^-26 |x|).
// ---------------------------------------------------------------------------
__global__ __launch_bounds__(256) void split3(
        const float* __restrict__ src, unsigned short* __restrict__ p1,
        unsigned short* __restrict__ p2, unsigned short* __restrict__ p3, int n4) {
    int i = blockIdx.x * 256 + threadIdx.x;
    int stride = gridDim.x * 256;
    for (; i < n4; i += stride) {
        float4 v = ((const float4*)src)[i];
        ushort4 a, b, c;
        float r;
        a.x = f2bf(v.x); r = v.x - bf2f(a.x); b.x = f2bf(r); c.x = f2bf(r - bf2f(b.x));
        a.y = f2bf(v.y); r = v.y - bf2f(a.y); b.y = f2bf(r); c.y = f2bf(r - bf2f(b.y));
        a.z = f2bf(v.z); r = v.z - bf2f(a.z); b.z = f2bf(r); c.z = f2bf(r - bf2f(b.z));
        a.w = f2bf(v.w); r = v.w - bf2f(a.w); b.w = f2bf(r); c.w = f2bf(r - bf2f(b.w));
        ((ushort4*)p1)[i] = a;
        ((ushort4*)p2)[i] = b;
        ((ushort4*)p3)[i] = c;
    }
}

// ---------------------------------------------------------------------------
// K1: ctx_fc = relu(context @ W^T) via 6-term bf16 MFMA (fp32-grade: err
// ~2^-24 rel -> far below the R2-passing 8e-6 att error level).
// A-tile 128 ctx rows, B-tile 64 W rows, BK=32; grid (128, 8) = 1024 blocks
// (4/CU). Waves: wn=(w>>1)*64 (A half), wm=(w&1)*32 (B half); per wave
// 64x32 = 4x2 frags of 16x16x32. Same staging/swizzle as att_mfma (proven).
// Epilogue: relu + RNE bf16 hi/lo split to Fhi/Flo (same arithmetic as R2).
// ---------------------------------------------------------------------------
__global__ __launch_bounds__(256, 3) void fc_mfma6(
        const unsigned short* __restrict__ A1, const unsigned short* __restrict__ A2,
        const unsigned short* __restrict__ A3, const unsigned short* __restrict__ B1,
        const unsigned short* __restrict__ B2, const unsigned short* __restrict__ B3,
        unsigned short* __restrict__ Fhi, unsigned short* __restrict__ Flo) {
    __shared__ char lds[36864];   // A planes 3x8192 @0, B planes 3x4096 @24576

    const int t     = threadIdx.x;
    const int mBase = blockIdx.x * 128;   // ctx-row tile
    const int hBase = blockIdx.y * 64;    // W-row (output col) tile
    const int w = t >> 6, lane = t & 63;
    const int q = lane >> 4, ln = lane & 15;
    const int wn = (w >> 1) * 64;
    const int wm = (w & 1) * 32;

    f32x4 acc[4][2] = {};

    for (int kt = 0; kt < 512; kt += 32) {
        // ---- stage A planes (128 rows x 32 k each = 512 x 16B chunks)
#pragma unroll
        for (int p = 0; p < 3; ++p) {
            const unsigned short* pl = (p == 0) ? A1 : (p == 1) ? A2 : A3;
#pragma unroll
            for (int rr = 0; rr < 2; ++rr) {
                int chunk = rr * 256 + t;
                int row   = chunk >> 2;
                int c     = (chunk & 3) ^ ((row >> 1) & 3);
                const unsigned short* g = pl + ((size_t)(mBase + row) * 512 + kt + c * 8);
                char* l = lds + p * 8192 + chunk * 16;
                __builtin_amdgcn_global_load_lds(
                    (const __attribute__((address_space(1))) void*)g,
                    (__attribute__((address_space(3))) void*)l, 16, 0, 0);
            }
        }
        // ---- stage B planes (64 rows x 32 k each = 256 x 16B chunks)
#pragma unroll
        for (int p = 0; p < 3; ++p) {
            const unsigned short* pl = (p == 0) ? B1 : (p == 1) ? B2 : B3;
            int chunk = t;
            int row   = chunk >> 2;
            int c     = (chunk & 3) ^ ((row >> 1) & 3);
            const unsigned short* g = pl + ((size_t)(hBase + row) * 512 + kt + c * 8);
            char* l = lds + 24576 + p * 4096 + chunk * 16;
            __builtin_amdgcn_global_load_lds(
                (const __attribute__((address_space(1))) void*)g,
                (__attribute__((address_space(3))) void*)l, 16, 0, 0);
        }
        __syncthreads();

        bf16x8 a1[4], a2[4], a3[4], b1[2], b2[2], b3[2];
#pragma unroll
        for (int i = 0; i < 4; ++i) {
            int mA = wn + i * 16 + ln;
            int oA = (mA * 4 + (q ^ ((mA >> 1) & 3))) * 16;
            a1[i] = *(const bf16x8*)(lds +     0 + oA);
            a2[i] = *(const bf16x8*)(lds +  8192 + oA);
            a3[i] = *(const bf16x8*)(lds + 16384 + oA);
        }
#pragma unroll
        for (int j = 0; j < 2; ++j) {
            int mB = wm + j * 16 + ln;
            int oB = (mB * 4 + (q ^ ((mB >> 1) & 3))) * 16;
            b1[j] = *(const bf16x8*)(lds + 24576 + oB);
            b2[j] = *(const bf16x8*)(lds + 28672 + oB);
            b3[j] = *(const bf16x8*)(lds + 32768 + oB);
        }
#pragma unroll
        for (int i = 0; i < 4; ++i)
#pragma unroll
            for (int j = 0; j < 2; ++j) {
                acc[i][j] = __builtin_amdgcn_mfma_f32_16x16x32_bf16(a1[i], b1[j], acc[i][j], 0, 0, 0);
                acc[i][j] = __builtin_amdgcn_mfma_f32_16x16x32_bf16(a1[i], b2[j], acc[i][j], 0, 0, 0);
                acc[i][j] = __builtin_amdgcn_mfma_f32_16x16x32_bf16(a2[i], b1[j], acc[i][j], 0, 0, 0);
                acc[i][j] = __builtin_amdgcn_mfma_f32_16x16x32_bf16(a2[i], b2[j], acc[i][j], 0, 0, 0);
                acc[i][j] = __builtin_amdgcn_mfma_f32_16x16x32_bf16(a1[i], b3[j], acc[i][j], 0, 0, 0);
                acc[i][j] = __builtin_amdgcn_mfma_f32_16x16x32_bf16(a3[i], b1[j], acc[i][j], 0, 0, 0);
            }
        __syncthreads();
    }

    // epilogue: C/D layout col=ln (W row), row=q*4+reg (ctx row)
#pragma unroll
    for (int j = 0; j < 2; ++j) {
        int h = hBase + wm + j * 16 + ln;
#pragma unroll
        for (int i = 0; i < 4; ++i) {
            int n0 = mBase + wn + i * 16 + q * 4;
#pragma unroll
            for (int r = 0; r < 4; ++r) {
                float v = fmaxf(acc[i][j][r], 0.f);
                unsigned short hi = f2bf(v);
                unsigned short lo = f2bf(v - bf2f(hi));
                size_t off = (size_t)(n0 + r) * 512 + h;
                Fhi[off] = hi;
                Flo[off] = lo;
            }
        }
    }
}

// ---------------------------------------------------------------------------
// K2: att = F F^T via bf16x3 MFMA emulation. VERBATIM from round 2 (passed).
// ---------------------------------------------------------------------------
__global__ __launch_bounds__(256, 2) void att_mfma(
        const unsigned short* __restrict__ Fhi, const unsigned short* __restrict__ Flo,
        const int* __restrict__ mask, float* __restrict__ out) {
    __shared__ char lds[32768];

    const int t     = threadIdx.x;
    const int b     = blockIdx.z;
    const int mBase = blockIdx.x * 128;
    const int nBase = blockIdx.y * 128;
    const int w    = t >> 6, lane = t & 63;
    const int q    = lane >> 4, ln = lane & 15;
    const int wn   = (w >> 1) * 64;
    const int wm   = (w & 1) * 64;
    const size_t rowB = (size_t)b * 2048;

    f32x4 acc[4][4] = {};

    for (int kt = 0; kt < 512; kt += 32) {
#pragma unroll
        for (int p = 0; p < 4; ++p) {
            const unsigned short* plane = (p & 1) ? Flo : Fhi;
            int rbase = (p < 2) ? nBase : mBase;
#pragma unroll
            for (int r = 0; r < 2; ++r) {
                int chunk = r * 256 + t;
                int row   = chunk >> 2;
                int cs    = chunk & 3;
                int c     = cs ^ ((row >> 1) & 3);
                const unsigned short* g =
                    plane + ((rowB + rbase + row) * 512 + kt + c * 8);
                char* l = lds + p * 8192 + chunk * 16;
                __builtin_amdgcn_global_load_lds(
                    (const __attribute__((address_space(1))) void*)g,
                    (__attribute__((address_space(3))) void*)l, 16, 0, 0);
            }
        }
        __syncthreads();

        bf16x8 ah[4], al[4], bh[4], bl[4];
#pragma unroll
        for (int i = 0; i < 4; ++i) {
            int mA = wn + i * 16 + ln;
            int oA = (mA * 4 + (q ^ ((mA >> 1) & 3))) * 16;
            ah[i] = *(const bf16x8*)(lds +     0 + oA);
            al[i] = *(const bf16x8*)(lds +  8192 + oA);
            int mB = wm + i * 16 + ln;
            int oB = (mB * 4 + (q ^ ((mB >> 1) & 3))) * 16;
            bh[i] = *(const bf16x8*)(lds + 16384 + oB);
            bl[i] = *(const bf16x8*)(lds + 24576 + oB);
        }
#pragma unroll
        for (int i = 0; i < 4; ++i)
#pragma unroll
            for (int j = 0; j < 4; ++j) {
                acc[i][j] = __builtin_amdgcn_mfma_f32_16x16x32_bf16(ah[i], bh[j], acc[i][j], 0, 0, 0);
                acc[i][j] = __builtin_amdgcn_mfma_f32_16x16x32_bf16(ah[i], bl[j], acc[i][j], 0, 0, 0);
                acc[i][j] = __builtin_amdgcn_mfma_f32_16x16x32_bf16(al[i], bh[j], acc[i][j], 0, 0, 0);
            }
        __syncthreads();
    }

    const int* mb = mask + b * 2048;
    float* outB = out + (size_t)b * 2048 * 2048;
#pragma unroll
    for (int j = 0; j < 4; ++j) {
        int mg   = mBase + wm + j * 16 + ln;
        int mcol = mb[mg];
#pragma unroll
        for (int i = 0; i < 4; ++i) {
            int n0 = nBase + wn + i * 16 + q * 4;
#pragma unroll
            for (int r = 0; r < 4; ++r) {
                int   n  = n0 + r;
                float v  = ((mb[n] != 0) & (mcol != 0)) ? acc[i][j][r] : NEG_INF;
                outB[(size_t)n * 2048 + mg] = v;
            }
        }
    }
}

// ---------------------------------------------------------------------------
// K3: per-row top-10 -> keep winners, fill -1e20. VERBATIM from round 2.
// ---------------------------------------------------------------------------
__device__ inline unsigned fkey(float f) {
    unsigned u = __float_as_uint(f);
    return (u & 0x80000000u) ? ~u : (u | 0x80000000u);
}

__global__ __launch_bounds__(256) void topk_rows(float* __restrict__ att) {
    __shared__ unsigned long long cand[40];
    __shared__ int   top_i[10];
    __shared__ float top_v[10];

    const int t    = threadIdx.x;
    const int lane = t & 63;
    const int w    = t >> 6;
    float* row = att + (size_t)blockIdx.x * 2048;

    float4 a = ((const float4*)row)[2 * t];
    float4 c = ((const float4*)row)[2 * t + 1];
    float v[8] = {a.x, a.y, a.z, a.w, c.x, c.y, c.z, c.w};

    unsigned long long key[8];
#pragma unroll
    for (int j = 0; j < 8; ++j)
        key[j] = ((unsigned long long)fkey(v[j]) << 32) |
                 (unsigned)(~(unsigned)(t * 8 + j));

    for (int r = 0; r < 10; ++r) {
        unsigned long long m = key[0];
#pragma unroll
        for (int j = 1; j < 8; ++j) m = (key[j] > m) ? key[j] : m;
#pragma unroll
        for (int off = 1; off < 64; off <<= 1) {
            unsigned long long o = __shfl_xor(m, off, 64);
            m = (o > m) ? o : m;
        }
        if (lane == 0) cand[w * 10 + r] = m;
#pragma unroll
        for (int j = 0; j < 8; ++j)
            if (key[j] == m) key[j] = 0ull;
    }
    __syncthreads();

    if (w == 0) {
        unsigned long long k2 = (lane < 40) ? cand[lane] : 0ull;
        for (int r = 0; r < 10; ++r) {
            unsigned long long m = k2;
#pragma unroll
            for (int off = 1; off < 64; off <<= 1) {
                unsigned long long o = __shfl_xor(m, off, 64);
                m = (o > m) ? o : m;
            }
            if (lane == r) {
                unsigned hu = (unsigned)(m >> 32);
                unsigned fu = (hu & 0x80000000u) ? (hu ^ 0x80000000u) : ~hu;
                top_v[r] = __uint_as_float(fu);
                top_i[r] = (int)(~(unsigned)(m & 0xffffffffu));
            }
            if (k2 == m) k2 = 0ull;
        }
    }
    __syncthreads();

    float o[8];
#pragma unroll
    for (int j = 0; j < 8; ++j) {
        int p   = t * 8 + j;
        float x = NEG_INF;
#pragma unroll
        for (int r = 0; r < 10; ++r)
            if (top_i[r] == p) x = top_v[r];
        o[j] = x;
    }
    ((float4*)row)[2 * t]     = make_float4(o[0], o[1], o[2], o[3]);
    ((float4*)row)[2 * t + 1] = make_float4(o[4], o[5], o[6], o[7]);
}

// ---------------------------------------------------------------------------
extern "C" void kernel_launch(void* const* d_in, const int* in_sizes, int n_in,
                              void* d_out, int out_size, void* d_ws, size_t ws_size,
                              hipStream_t stream) {
    const float* ctx  = (const float*)d_in[0];   // [8, 2048, 512]
    const float* W    = (const float*)d_in[1];   // [512, 512]
    const int*   mask = (const int*)d_in[2];     // [8, 2048]
    float* out = (float*)d_out;                  // [8, 2048, 2048]

    // bf16 triple-planes for ctx and W live in d_out (dead until att_mfma)
    const size_t CN = (size_t)16384 * 512;       // 8,388,608
    const size_t WN = (size_t)512 * 512;         // 262,144
    unsigned short* C1 = (unsigned short*)d_out;
    unsigned short* C2 = C1 + CN;
    unsigned short* C3 = C2 + CN;
    unsigned short* W1 = C3 + CN;
    unsigned short* W2 = W1 + WN;
    unsigned short* W3 = W2 + WN;                // ends at 51.9 MB < 134 MB

    unsigned short* Fhi = (unsigned short*)d_ws;           // [16384, 512] bf16
    unsigned short* Flo = Fhi + CN;

    dim3 blk(256);
    split3<<<dim3(2048), blk, 0, stream>>>(ctx, C1, C2, C3, 2097152);
    split3<<<dim3(256),  blk, 0, stream>>>(W,   W1, W2, W3, 65536);
    fc_mfma6<<<dim3(128, 8), blk, 0, stream>>>(C1, C2, C3, W1, W2, W3, Fhi, Flo);
    att_mfma<<<dim3(16, 16, 8), blk, 0, stream>>>(Fhi, Flo, mask, out);
    topk_rows<<<dim3(16384), blk, 0, stream>>>(out);
}

// Round 6
// 384.956 us; speedup vs baseline: 2.0634x; 1.0990x over previous
//
#include <hip/hip_runtime.h>
#include <hip/hip_bf16.h>

#define NEG_INF -1e20f

typedef __bf16 bf16x8 __attribute__((ext_vector_type(8)));
typedef float  f32x4  __attribute__((ext_vector_type(4)));

__device__ inline unsigned short f2bf(float x) {            // RNE, no NaN inputs
    unsigned u = __float_as_uint(x);
    unsigned r = u + 0x7fffu + ((u >> 16) & 1u);
    return (unsigned short)(r >> 16);
}
__device__ inline float bf2f(unsigned short h) {
    return __uint_as_float((unsigned)h << 16);
}

// ---------------------------------------------------------------------------
// K0: split fp32 -> 3 bf16 planes (x ~= b1 + b2 + b3, residual ~2^-26 |x|).
// ---------------------------------------------------------------------------
__global__ __launch_bounds__(256) void split3(
        const float* __restrict__ src, unsigned short* __restrict__ p1,
        unsigned short* __restrict__ p2, unsigned short* __restrict__ p3, int n4) {
    int i = blockIdx.x * 256 + threadIdx.x;
    int stride = gridDim.x * 256;
    for (; i < n4; i += stride) {
        float4 v = ((const float4*)src)[i];
        ushort4 a, b, c;
        float r;
        a.x = f2bf(v.x); r = v.x - bf2f(a.x); b.x = f2bf(r); c.x = f2bf(r - bf2f(b.x));
        a.y = f2bf(v.y); r = v.y - bf2f(a.y); b.y = f2bf(r); c.y = f2bf(r - bf2f(b.y));
        a.z = f2bf(v.z); r = v.z - bf2f(a.z); b.z = f2bf(r); c.z = f2bf(r - bf2f(b.z));
        a.w = f2bf(v.w); r = v.w - bf2f(a.w); b.w = f2bf(r); c.w = f2bf(r - bf2f(b.w));
        ((ushort4*)p1)[i] = a;
        ((ushort4*)p2)[i] = b;
        ((ushort4*)p3)[i] = c;
    }
}

// ---------------------------------------------------------------------------
// K1: ctx_fc = relu(context @ W^T) via 6-term bf16 MFMA. VERBATIM from R5.
// ---------------------------------------------------------------------------
__global__ __launch_bounds__(256, 3) void fc_mfma6(
        const unsigned short* __restrict__ A1, const unsigned short* __restrict__ A2,
        const unsigned short* __restrict__ A3, const unsigned short* __restrict__ B1,
        const unsigned short* __restrict__ B2, const unsigned short* __restrict__ B3,
        unsigned short* __restrict__ Fhi, unsigned short* __restrict__ Flo) {
    __shared__ char lds[36864];   // A planes 3x8192 @0, B planes 3x4096 @24576

    const int t     = threadIdx.x;
    const int mBase = blockIdx.x * 128;   // ctx-row tile
    const int hBase = blockIdx.y * 64;    // W-row (output col) tile
    const int w = t >> 6, lane = t & 63;
    const int q = lane >> 4, ln = lane & 15;
    const int wn = (w >> 1) * 64;
    const int wm = (w & 1) * 32;

    f32x4 acc[4][2] = {};

    for (int kt = 0; kt < 512; kt += 32) {
#pragma unroll
        for (int p = 0; p < 3; ++p) {
            const unsigned short* pl = (p == 0) ? A1 : (p == 1) ? A2 : A3;
#pragma unroll
            for (int rr = 0; rr < 2; ++rr) {
                int chunk = rr * 256 + t;
                int row   = chunk >> 2;
                int c     = (chunk & 3) ^ ((row >> 1) & 3);
                const unsigned short* g = pl + ((size_t)(mBase + row) * 512 + kt + c * 8);
                char* l = lds + p * 8192 + chunk * 16;
                __builtin_amdgcn_global_load_lds(
                    (const __attribute__((address_space(1))) void*)g,
                    (__attribute__((address_space(3))) void*)l, 16, 0, 0);
            }
        }
#pragma unroll
        for (int p = 0; p < 3; ++p) {
            const unsigned short* pl = (p == 0) ? B1 : (p == 1) ? B2 : B3;
            int chunk = t;
            int row   = chunk >> 2;
            int c     = (chunk & 3) ^ ((row >> 1) & 3);
            const unsigned short* g = pl + ((size_t)(hBase + row) * 512 + kt + c * 8);
            char* l = lds + 24576 + p * 4096 + chunk * 16;
            __builtin_amdgcn_global_load_lds(
                (const __attribute__((address_space(1))) void*)g,
                (__attribute__((address_space(3))) void*)l, 16, 0, 0);
        }
        __syncthreads();

        bf16x8 a1[4], a2[4], a3[4], b1[2], b2[2], b3[2];
#pragma unroll
        for (int i = 0; i < 4; ++i) {
            int mA = wn + i * 16 + ln;
            int oA = (mA * 4 + (q ^ ((mA >> 1) & 3))) * 16;
            a1[i] = *(const bf16x8*)(lds +     0 + oA);
            a2[i] = *(const bf16x8*)(lds +  8192 + oA);
            a3[i] = *(const bf16x8*)(lds + 16384 + oA);
        }
#pragma unroll
        for (int j = 0; j < 2; ++j) {
            int mB = wm + j * 16 + ln;
            int oB = (mB * 4 + (q ^ ((mB >> 1) & 3))) * 16;
            b1[j] = *(const bf16x8*)(lds + 24576 + oB);
            b2[j] = *(const bf16x8*)(lds + 28672 + oB);
            b3[j] = *(const bf16x8*)(lds + 32768 + oB);
        }
#pragma unroll
        for (int i = 0; i < 4; ++i)
#pragma unroll
            for (int j = 0; j < 2; ++j) {
                acc[i][j] = __builtin_amdgcn_mfma_f32_16x16x32_bf16(a1[i], b1[j], acc[i][j], 0, 0, 0);
                acc[i][j] = __builtin_amdgcn_mfma_f32_16x16x32_bf16(a1[i], b2[j], acc[i][j], 0, 0, 0);
                acc[i][j] = __builtin_amdgcn_mfma_f32_16x16x32_bf16(a2[i], b1[j], acc[i][j], 0, 0, 0);
                acc[i][j] = __builtin_amdgcn_mfma_f32_16x16x32_bf16(a2[i], b2[j], acc[i][j], 0, 0, 0);
                acc[i][j] = __builtin_amdgcn_mfma_f32_16x16x32_bf16(a1[i], b3[j], acc[i][j], 0, 0, 0);
                acc[i][j] = __builtin_amdgcn_mfma_f32_16x16x32_bf16(a3[i], b1[j], acc[i][j], 0, 0, 0);
            }
        __syncthreads();
    }

#pragma unroll
    for (int j = 0; j < 2; ++j) {
        int h = hBase + wm + j * 16 + ln;
#pragma unroll
        for (int i = 0; i < 4; ++i) {
            int n0 = mBase + wn + i * 16 + q * 4;
#pragma unroll
            for (int r = 0; r < 4; ++r) {
                float v = fmaxf(acc[i][j][r], 0.f);
                unsigned short hi = f2bf(v);
                unsigned short lo = f2bf(v - bf2f(hi));
                size_t off = (size_t)(n0 + r) * 512 + h;
                Fhi[off] = hi;
                Flo[off] = lo;
            }
        }
    }
}

// ---------------------------------------------------------------------------
// K2: att = F F^T via bf16x3 MFMA emulation. VERBATIM from round 2 (passed).
// ---------------------------------------------------------------------------
__global__ __launch_bounds__(256, 2) void att_mfma(
        const unsigned short* __restrict__ Fhi, const unsigned short* __restrict__ Flo,
        const int* __restrict__ mask, float* __restrict__ out) {
    __shared__ char lds[32768];

    const int t     = threadIdx.x;
    const int b     = blockIdx.z;
    const int mBase = blockIdx.x * 128;
    const int nBase = blockIdx.y * 128;
    const int w    = t >> 6, lane = t & 63;
    const int q    = lane >> 4, ln = lane & 15;
    const int wn   = (w >> 1) * 64;
    const int wm   = (w & 1) * 64;
    const size_t rowB = (size_t)b * 2048;

    f32x4 acc[4][4] = {};

    for (int kt = 0; kt < 512; kt += 32) {
#pragma unroll
        for (int p = 0; p < 4; ++p) {
            const unsigned short* plane = (p & 1) ? Flo : Fhi;
            int rbase = (p < 2) ? nBase : mBase;
#pragma unroll
            for (int r = 0; r < 2; ++r) {
                int chunk = r * 256 + t;
                int row   = chunk >> 2;
                int cs    = chunk & 3;
                int c     = cs ^ ((row >> 1) & 3);
                const unsigned short* g =
                    plane + ((rowB + rbase + row) * 512 + kt + c * 8);
                char* l = lds + p * 8192 + chunk * 16;
                __builtin_amdgcn_global_load_lds(
                    (const __attribute__((address_space(1))) void*)g,
                    (__attribute__((address_space(3))) void*)l, 16, 0, 0);
            }
        }
        __syncthreads();

        bf16x8 ah[4], al[4], bh[4], bl[4];
#pragma unroll
        for (int i = 0; i < 4; ++i) {
            int mA = wn + i * 16 + ln;
            int oA = (mA * 4 + (q ^ ((mA >> 1) & 3))) * 16;
            ah[i] = *(const bf16x8*)(lds +     0 + oA);
            al[i] = *(const bf16x8*)(lds +  8192 + oA);
            int mB = wm + i * 16 + ln;
            int oB = (mB * 4 + (q ^ ((mB >> 1) & 3))) * 16;
            bh[i] = *(const bf16x8*)(lds + 16384 + oB);
            bl[i] = *(const bf16x8*)(lds + 24576 + oB);
        }
#pragma unroll
        for (int i = 0; i < 4; ++i)
#pragma unroll
            for (int j = 0; j < 4; ++j) {
                acc[i][j] = __builtin_amdgcn_mfma_f32_16x16x32_bf16(ah[i], bh[j], acc[i][j], 0, 0, 0);
                acc[i][j] = __builtin_amdgcn_mfma_f32_16x16x32_bf16(ah[i], bl[j], acc[i][j], 0, 0, 0);
                acc[i][j] = __builtin_amdgcn_mfma_f32_16x16x32_bf16(al[i], bh[j], acc[i][j], 0, 0, 0);
            }
        __syncthreads();
    }

    const int* mb = mask + b * 2048;
    float* outB = out + (size_t)b * 2048 * 2048;
#pragma unroll
    for (int j = 0; j < 4; ++j) {
        int mg   = mBase + wm + j * 16 + ln;
        int mcol = mb[mg];
#pragma unroll
        for (int i = 0; i < 4; ++i) {
            int n0 = nBase + wn + i * 16 + q * 4;
#pragma unroll
            for (int r = 0; r < 4; ++r) {
                int   n  = n0 + r;
                float v  = ((mb[n] != 0) & (mcol != 0)) ? acc[i][j][r] : NEG_INF;
                outB[(size_t)n * 2048 + mg] = v;
            }
        }
    }
}

// ---------------------------------------------------------------------------
// K3: per-row top-10 -> keep winners, fill -1e20.  v2: u32-key butterfly +
// ballot lane-pick + incremental local argmax + LDS-patch rewrite.
// Selection semantics identical to v1 (lowest index on ties, fkey bijection).
// ---------------------------------------------------------------------------
__device__ inline unsigned fkey(float f) {
    unsigned u = __float_as_uint(f);
    return (u & 0x80000000u) ? ~u : (u | 0x80000000u);
}

__global__ __launch_bounds__(256) void topk_rows(float* __restrict__ att) {
    __shared__ float patch[2048];
    __shared__ unsigned long long cand[40];
    __shared__ int   top_i[10];
    __shared__ float top_v[10];

    const int t    = threadIdx.x;
    const int lane = t & 63;
    const int w    = t >> 6;
    float* row = att + (size_t)blockIdx.x * 2048;

    float4 a = ((const float4*)row)[2 * t];
    float4 c = ((const float4*)row)[2 * t + 1];
    float v[8] = {a.x, a.y, a.z, a.w, c.x, c.y, c.z, c.w};

    unsigned key[8];
#pragma unroll
    for (int j = 0; j < 8; ++j) key[j] = fkey(v[j]);

    // local argmax (strict >, ascending scan => lowest idx on in-lane ties)
    unsigned lk = key[0]; int lj = 0;
#pragma unroll
    for (int j = 1; j < 8; ++j)
        if (key[j] > lk) { lk = key[j]; lj = j; }

    // per-wave top-10 of its 512 elements
    for (int r = 0; r < 10; ++r) {
        unsigned M = lk;
#pragma unroll
        for (int off = 1; off < 64; off <<= 1) {
            unsigned o = __shfl_xor(M, off, 64);
            M = (o > M) ? o : M;
        }
        unsigned long long ball = __ballot(lk == M);
        int src  = __ffsll(ball) - 1;               // lowest lane = lowest idx
        int widx = __shfl(t * 8 + lj, src, 64);
        if (lane == 0)
            cand[w * 10 + r] =
                ((unsigned long long)M << 32) | (unsigned)(~(unsigned)widx);
        if (lane == src) {                          // purge + rescan (winner lane only)
            key[lj] = 0u;
            lk = key[0]; lj = 0;
#pragma unroll
            for (int j = 1; j < 8; ++j)
                if (key[j] > lk) { lk = key[j]; lj = j; }
        }
    }
    __syncthreads();

    // wave 0: top-10 of the 40 candidates (u64 keys, ~idx tie-break)
    if (w == 0) {
        unsigned long long k2 = (lane < 40) ? cand[lane] : 0ull;
        for (int r = 0; r < 10; ++r) {
            unsigned long long m = k2;
#pragma unroll
            for (int off = 1; off < 64; off <<= 1) {
                unsigned long long o = __shfl_xor(m, off, 64);
                m = (o > m) ? o : m;
            }
            if (lane == r) {
                unsigned hu = (unsigned)(m >> 32);
                unsigned fu = (hu & 0x80000000u) ? (hu ^ 0x80000000u) : ~hu;
                top_v[r] = __uint_as_float(fu);
                top_i[r] = (int)(~(unsigned)(m & 0xffffffffu));
            }
            if (k2 == m) k2 = 0ull;
        }
    }

    // build the output row in LDS: -1e20 fill + scatter 10 winners
    float4 ninf4 = make_float4(NEG_INF, NEG_INF, NEG_INF, NEG_INF);
    ((float4*)patch)[2 * t]     = ninf4;
    ((float4*)patch)[2 * t + 1] = ninf4;
    __syncthreads();
    if (t < 10) patch[top_i[t]] = top_v[t];         // distinct indices: race-free
    __syncthreads();
    ((float4*)row)[2 * t]     = ((float4*)patch)[2 * t];
    ((float4*)row)[2 * t + 1] = ((float4*)patch)[2 * t + 1];
}

// ---------------------------------------------------------------------------
extern "C" void kernel_launch(void* const* d_in, const int* in_sizes, int n_in,
                              void* d_out, int out_size, void* d_ws, size_t ws_size,
                              hipStream_t stream) {
    const float* ctx  = (const float*)d_in[0];   // [8, 2048, 512]
    const float* W    = (const float*)d_in[1];   // [512, 512]
    const int*   mask = (const int*)d_in[2];     // [8, 2048]
    float* out = (float*)d_out;                  // [8, 2048, 2048]

    // bf16 triple-planes for ctx and W live in d_out (dead until att_mfma)
    const size_t CN = (size_t)16384 * 512;       // 8,388,608
    const size_t WN = (size_t)512 * 512;         // 262,144
    unsigned short* C1 = (unsigned short*)d_out;
    unsigned short* C2 = C1 + CN;
    unsigned short* C3 = C2 + CN;
    unsigned short* W1 = C3 + CN;
    unsigned short* W2 = W1 + WN;
    unsigned short* W3 = W2 + WN;                // ends at 51.9 MB < 134 MB

    unsigned short* Fhi = (unsigned short*)d_ws;           // [16384, 512] bf16
    unsigned short* Flo = Fhi + CN;

    dim3 blk(256);
    split3<<<dim3(2048), blk, 0, stream>>>(ctx, C1, C2, C3, 2097152);
    split3<<<dim3(256),  blk, 0, stream>>>(W,   W1, W2, W3, 65536);
    fc_mfma6<<<dim3(128, 8), blk, 0, stream>>>(C1, C2, C3, W1, W2, W3, Fhi, Flo);
    att_mfma<<<dim3(16, 16, 8), blk, 0, stream>>>(Fhi, Flo, mask, out);
    topk_rows<<<dim3(16384), blk, 0, stream>>>(out);
}